// Round 1
// baseline (1240.964 us; speedup 1.0000x reference)
//
#include <hip/hip_runtime.h>

#define T_DIM 1024
#define D_DIM 512
#define M_CODES 2048
#define NT 32768            // 32*1024 query rows
#define TOTAL 16777216      // NT*D_DIM

// ---- workspace layout (bytes) ----
#define WS_MU    0                       // 16384 f32
#define WS_S     (WS_MU   + 65536)      // 16384 f32
#define WS_RINV  (WS_S    + 65536)      // 16384 f32
#define WS_CZ    (WS_RINV + 65536)      // 32768 f32
#define WS_CE    (WS_CZ   + 131072)     // 2048 f32
#define WS_KEYS  (WS_CE   + 8192)       // 32768 u64
#define WS_EMBN  (WS_KEYS + 262144)     // 2048*512 f32
#define WS_HIST  (WS_EMBN + 4194304)    // 2048 u32
#define WS_LOSS  (WS_HIST + 8192)       // 1 f32

__device__ __forceinline__ float block_reduce_sum_256(float v) {
    #pragma unroll
    for (int s = 32; s; s >>= 1) v += __shfl_xor(v, s, 64);
    __shared__ float ls[4];
    int w = threadIdx.x >> 6;
    if ((threadIdx.x & 63) == 0) ls[w] = v;
    __syncthreads();
    float r = (ls[0] + ls[1]) + (ls[2] + ls[3]);
    __syncthreads();
    return r;
}

// ---- instance-norm stats over T per (n,d): mu, s=std+eps, rinv=1/s ----
__global__ void stats_kernel(const float* __restrict__ x,
                             float* __restrict__ mu_o, float* __restrict__ s_o,
                             float* __restrict__ rinv_o) {
    int n = blockIdx.y;
    int lane = threadIdx.x & 63;
    int d = blockIdx.x * 64 + lane;
    int tg = threadIdx.x >> 6;
    const float* xp = x + (size_t)n * (T_DIM * D_DIM) + d;
    float sum = 0.f, sq = 0.f;
    int t0 = tg * 256;
    for (int it = 0; it < 256; ++it) {
        float v = xp[(size_t)(t0 + it) * D_DIM];
        sum += v; sq += v * v;
    }
    __shared__ float ssum[4][64], ssq[4][64];
    ssum[tg][lane] = sum;
    ssq[tg][lane] = sq;
    __syncthreads();
    if (threadIdx.x < 64) {
        int l = threadIdx.x;
        float s1 = (ssum[0][l] + ssum[1][l]) + (ssum[2][l] + ssum[3][l]);
        float q1 = (ssq[0][l] + ssq[1][l]) + (ssq[2][l] + ssq[3][l]);
        float mu = s1 * (1.0f / 1024.0f);            // /1024 exact
        float var = (q1 - 1024.0f * mu * mu) * (1.0f / 1023.0f);
        var = fmaxf(var, 0.0f);
        float sd = sqrtf(var) + 1e-5f;
        int nd = n * D_DIM + blockIdx.x * 64 + l;
        mu_o[nd] = mu; s_o[nd] = sd; rinv_o[nd] = 1.0f / sd;
    }
}

// ---- codebook prep: emb_n = e/(||e||+1e-4), ce = sum(emb_n^2) ----
__global__ void codebook_kernel(const float* __restrict__ emb,
                                float* __restrict__ embn, float* __restrict__ ce) {
    int j = blockIdx.x;
    const float* ep = emb + (size_t)j * D_DIM;
    int d = threadIdx.x * 2;
    float2 e = *(const float2*)&ep[d];
    float sq = e.x * e.x + e.y * e.y;
    float norm2 = block_reduce_sum_256(sq);
    float den = sqrtf(norm2) + 1e-4f;
    float en0 = e.x / den, en1 = e.y / den;
    *(float2*)&embn[(size_t)j * D_DIM + d] = make_float2(en0, en1);
    float cep = en0 * en0 + en1 * en1;
    float cesum = block_reduce_sum_256(cep);
    if (threadIdx.x == 0) ce[j] = cesum;
}

// ---- cz_i = sum_d z^2 ----
__global__ void cz_kernel(const float* __restrict__ x, const float* __restrict__ mu,
                          const float* __restrict__ rinv, float* __restrict__ cz) {
    int i = blockIdx.x * 4 + (threadIdx.x >> 6);
    int lane = threadIdx.x & 63;
    int n = i >> 10;
    const float* xp = x + (size_t)i * D_DIM;
    const float* mp = mu + n * D_DIM;
    const float* rp = rinv + n * D_DIM;
    float acc = 0.f;
    #pragma unroll
    for (int c = 0; c < 2; ++c) {
        int d = c * 256 + lane * 4;
        float4 xv = *(const float4*)&xp[d];
        float4 mv = *(const float4*)&mp[d];
        float4 rv = *(const float4*)&rp[d];
        float z0 = (xv.x - mv.x) * rv.x;
        float z1 = (xv.y - mv.y) * rv.y;
        float z2 = (xv.z - mv.z) * rv.z;
        float z3 = (xv.w - mv.w) * rv.w;
        acc += z0 * z0 + z1 * z1 + z2 * z2 + z3 * z3;
    }
    #pragma unroll
    for (int s = 32; s; s >>= 1) acc += __shfl_xor(acc, s, 64);
    if (lane == 0) cz[i] = acc;
}

// ---- fused normalize + GEMM + argmin ----
__global__ __launch_bounds__(256, 2) void gemm_argmin(
    const float* __restrict__ x, const float* __restrict__ mu,
    const float* __restrict__ rinv, const float* __restrict__ embn,
    const float* __restrict__ ce, const float* __restrict__ cz,
    unsigned long long* __restrict__ keys) {
    __shared__ float As[32][132];   // [k][m], +4 pad: 16B-aligned rows, spread banks
    __shared__ float Bs[32][132];
    int tid = threadIdx.x;
    int n0 = blockIdx.x * 128;
    int m0 = blockIdx.y * 128;
    float acc[8][8];
    #pragma unroll
    for (int q = 0; q < 8; ++q)
        #pragma unroll
        for (int j = 0; j < 8; ++j) acc[q][j] = 0.f;

    int srow = tid >> 3;            // 0..31
    int scol = (tid & 7) << 2;      // 0,4,..,28
    int ty = tid >> 4;              // 0..15
    int tx = tid & 15;              // 0..15

    for (int kc = 0; kc < 512; kc += 32) {
        __syncthreads();
        #pragma unroll
        for (int p = 0; p < 4; ++p) {
            int m = srow + 32 * p;
            size_t gi = (size_t)(m0 + m);
            int n = (int)(gi >> 10);
            int d = kc + scol;
            float4 xv = *(const float4*)&x[gi * 512 + d];
            float4 mv = *(const float4*)&mu[n * 512 + d];
            float4 rv = *(const float4*)&rinv[n * 512 + d];
            As[scol + 0][m] = (xv.x - mv.x) * rv.x;
            As[scol + 1][m] = (xv.y - mv.y) * rv.y;
            As[scol + 2][m] = (xv.z - mv.z) * rv.z;
            As[scol + 3][m] = (xv.w - mv.w) * rv.w;
            float4 ev = *(const float4*)&embn[(size_t)(n0 + m) * 512 + d];
            Bs[scol + 0][m] = ev.x;
            Bs[scol + 1][m] = ev.y;
            Bs[scol + 2][m] = ev.z;
            Bs[scol + 3][m] = ev.w;
        }
        __syncthreads();
        #pragma unroll
        for (int k = 0; k < 32; ++k) {
            float a[8], b[8];
            *(float4*)&a[0] = *(const float4*)&As[k][ty * 4];
            *(float4*)&a[4] = *(const float4*)&As[k][64 + ty * 4];
            *(float4*)&b[0] = *(const float4*)&Bs[k][tx * 4];
            *(float4*)&b[4] = *(const float4*)&Bs[k][64 + tx * 4];
            #pragma unroll
            for (int q = 0; q < 8; ++q)
                #pragma unroll
                for (int j = 0; j < 8; ++j)
                    acc[q][j] += a[q] * b[j];
        }
    }

    #pragma unroll
    for (int qq = 0; qq < 8; ++qq) {
        int qm = (qq < 4) ? (ty * 4 + qq) : (64 + ty * 4 + (qq - 4));
        int q = m0 + qm;
        float czq = cz[q];
        unsigned long long best = ~0ULL;
        #pragma unroll
        for (int jj = 0; jj < 8; ++jj) {
            int jn = (jj < 4) ? (tx * 4 + jj) : (64 + tx * 4 + (jj - 4));
            int j = n0 + jn;
            // mimic ref rounding: (ce+cz) - 2*dot ; *2 is exact so fma==separate
            float dist = (ce[j] + czq) - 2.0f * acc[qq][jj];
            unsigned long long key =
                ((unsigned long long)__float_as_uint(dist) << 32) | (unsigned)j;
            if (key < best) best = key;
        }
        #pragma unroll
        for (int s = 1; s < 16; s <<= 1) {
            unsigned long long o = __shfl_xor(best, s, 64);
            if (o < best) best = o;
        }
        if (tx == 0) atomicMin(keys + q, best);
    }
}

// ---- gather + STE output + loss + histogram ----
__global__ void output_kernel(const float* __restrict__ x, const float* __restrict__ mu,
                              const float* __restrict__ s, const float* __restrict__ emb,
                              const unsigned long long* __restrict__ keys,
                              float* __restrict__ out, float* __restrict__ loss_acc,
                              unsigned* __restrict__ hist) {
    int i = blockIdx.x;
    int n = i >> 10;
    unsigned idx = (unsigned)(keys[i] & 0xFFFFFFFFULL);
    int d = threadIdx.x * 2;
    float2 xv = *(const float2*)&x[(size_t)i * 512 + d];
    float2 mv = *(const float2*)&mu[n * 512 + d];
    float2 sv = *(const float2*)&s[n * 512 + d];
    float2 ev = *(const float2*)&emb[(size_t)idx * 512 + d];
    float z0 = (xv.x - mv.x) / sv.x;
    float z1 = (xv.y - mv.y) / sv.y;
    // quantized_ste = z + (q - z); out = (ste + q)/2  (mimic fp ops)
    float o0 = ((z0 + (ev.x - z0)) + ev.x) * 0.5f;
    float o1 = ((z1 + (ev.y - z1)) + ev.y) * 0.5f;
    *(float2*)&out[(size_t)i * 512 + d] = make_float2(o0, o1);
    float l = (z0 - ev.x) * (z0 - ev.x) + (z1 - ev.y) * (z1 - ev.y);
    l = block_reduce_sum_256(l);
    if (threadIdx.x == 0) {
        atomicAdd(loss_acc, l);
        atomicAdd(&hist[idx], 1u);
    }
}

// ---- scalars: loss mean + perplexity ----
__global__ void final_kernel(const unsigned* __restrict__ hist,
                             const float* __restrict__ loss_acc, float* __restrict__ out) {
    float h = 0.f;
    for (int b = threadIdx.x; b < M_CODES; b += 256) {
        float p = (float)hist[b] * (1.0f / 32768.0f);
        h += p * logf(p + 1e-10f);
    }
    h = block_reduce_sum_256(h);
    if (threadIdx.x == 0) {
        out[TOTAL] = loss_acc[0] * (1.0f / 16777216.0f);
        out[TOTAL + 1] = expf(-h);
    }
}

extern "C" void kernel_launch(void* const* d_in, const int* in_sizes, int n_in,
                              void* d_out, int out_size, void* d_ws, size_t ws_size,
                              hipStream_t stream) {
    (void)in_sizes; (void)n_in; (void)out_size; (void)ws_size;
    const float* x = (const float*)d_in[0];
    const float* emb = (const float*)d_in[1];
    float* out = (float*)d_out;
    char* ws = (char*)d_ws;
    float* mu   = (float*)(ws + WS_MU);
    float* s    = (float*)(ws + WS_S);
    float* rinv = (float*)(ws + WS_RINV);
    float* cz   = (float*)(ws + WS_CZ);
    float* ce   = (float*)(ws + WS_CE);
    unsigned long long* keys = (unsigned long long*)(ws + WS_KEYS);
    float* embn = (float*)(ws + WS_EMBN);
    unsigned* hist = (unsigned*)(ws + WS_HIST);
    float* loss_acc = (float*)(ws + WS_LOSS);

    hipMemsetAsync(ws + WS_KEYS, 0xFF, 262144, stream);
    hipMemsetAsync(ws + WS_HIST, 0x00, 8192 + 16, stream);

    stats_kernel<<<dim3(8, 32), 256, 0, stream>>>(x, mu, s, rinv);
    codebook_kernel<<<M_CODES, 256, 0, stream>>>(emb, embn, ce);
    cz_kernel<<<NT / 4, 256, 0, stream>>>(x, mu, rinv, cz);
    gemm_argmin<<<dim3(16, 256), 256, 0, stream>>>(x, mu, rinv, embn, ce, cz, keys);
    output_kernel<<<NT, 256, 0, stream>>>(x, mu, s, emb, keys, out, loss_acc, hist);
    final_kernel<<<1, 256, 0, stream>>>(hist, loss_acc, out);
}

// Round 3
// 816.761 us; speedup vs baseline: 1.5194x; 1.5194x over previous
//
#include <hip/hip_runtime.h>

#define T_DIM 1024
#define D_DIM 512
#define M_CODES 2048
#define NT 32768            // 32*1024 query rows
#define TOTAL 16777216      // NT*D_DIM

typedef _Float16 h2 __attribute__((ext_vector_type(2)));
typedef _Float16 h4 __attribute__((ext_vector_type(4)));
typedef _Float16 h8 __attribute__((ext_vector_type(8)));
typedef float f32x4 __attribute__((ext_vector_type(4)));

// ---- workspace layout (bytes) ----
#define WS_MU    0                        // 16384 f32
#define WS_S     65536                    // 16384 f32
#define WS_CZ    131072                   // 32768 f32
#define WS_CE    262144                   // 2048 f32
#define WS_KEYS  270336                   // 32768 u64
#define WS_EH    532480                   // 2048*512 f16
#define WS_EL    (532480 + 2097152)       // 2048*512 f16
#define WS_HIST  (532480 + 4194304)       // 2048 u32
#define WS_LOSS  (WS_HIST + 8192)         // 1 f32

__device__ __forceinline__ float block_reduce_sum_256(float v) {
    #pragma unroll
    for (int s = 32; s; s >>= 1) v += __shfl_xor(v, s, 64);
    __shared__ float ls[4];
    int w = threadIdx.x >> 6;
    if ((threadIdx.x & 63) == 0) ls[w] = v;
    __syncthreads();
    float r = (ls[0] + ls[1]) + (ls[2] + ls[3]);
    __syncthreads();
    return r;
}

struct Split { _Float16 hi, lo; };
// v = hi + lo*2^-11 with hi,lo fp16 (lo pre-scaled by 2^11 to stay normal)
__device__ __forceinline__ Split split16(float v) {
    Split r;
    _Float16 h = (_Float16)v;
    float res = v - (float)h;            // exact (Sterbenz)
    r.hi = h;
    r.lo = (_Float16)(res * 2048.0f);    // scale exact
    return r;
}

// ---- instance-norm stats over T per (n,d): mu, s=std+eps ----
__global__ void stats_kernel(const float* __restrict__ x,
                             float* __restrict__ mu_o, float* __restrict__ s_o) {
    int n = blockIdx.y;
    int lane = threadIdx.x & 63;
    int d = blockIdx.x * 64 + lane;
    int tg = threadIdx.x >> 6;
    const float* xp = x + (size_t)n * (T_DIM * D_DIM) + d;
    float sum = 0.f, sq = 0.f;
    int t0 = tg * 256;
    for (int it = 0; it < 256; ++it) {
        float v = xp[(size_t)(t0 + it) * D_DIM];
        sum += v; sq += v * v;
    }
    __shared__ float ssum[4][64], ssq[4][64];
    ssum[tg][lane] = sum;
    ssq[tg][lane] = sq;
    __syncthreads();
    if (threadIdx.x < 64) {
        int l = threadIdx.x;
        float s1 = (ssum[0][l] + ssum[1][l]) + (ssum[2][l] + ssum[3][l]);
        float q1 = (ssq[0][l] + ssq[1][l]) + (ssq[2][l] + ssq[3][l]);
        float mu = s1 * (1.0f / 1024.0f);
        float var = (q1 - 1024.0f * mu * mu) * (1.0f / 1023.0f);
        var = fmaxf(var, 0.0f);
        float sd = sqrtf(var) + 1e-5f;
        int nd = n * D_DIM + blockIdx.x * 64 + l;
        mu_o[nd] = mu; s_o[nd] = sd;
    }
}

// ---- codebook prep: emb_n split to f16 hi/lo, ce = sum(emb_n^2) ----
__global__ void codebook_kernel(const float* __restrict__ emb,
                                _Float16* __restrict__ eh, _Float16* __restrict__ el,
                                float* __restrict__ ce) {
    int j = blockIdx.x;
    int d = threadIdx.x * 2;
    float2 e = *(const float2*)&emb[(size_t)j * D_DIM + d];
    float sq = e.x * e.x + e.y * e.y;
    float norm2 = block_reduce_sum_256(sq);
    float den = sqrtf(norm2) + 1e-4f;
    float en0 = e.x / den, en1 = e.y / den;
    Split s0 = split16(en0), s1 = split16(en1);
    h2 hv, lv;
    hv[0] = s0.hi; hv[1] = s1.hi;
    lv[0] = s0.lo; lv[1] = s1.lo;
    *(h2*)&eh[(size_t)j * D_DIM + d] = hv;
    *(h2*)&el[(size_t)j * D_DIM + d] = lv;
    float cep = en0 * en0 + en1 * en1;
    float cesum = block_reduce_sum_256(cep);
    if (threadIdx.x == 0) ce[j] = cesum;
}

// ---- z = (x-mu)/s exactly like ref; write f16 split + cz = ||z||^2 ----
__global__ void cz_split_kernel(const float* __restrict__ x, const float* __restrict__ mu,
                                const float* __restrict__ s, float* __restrict__ cz,
                                _Float16* __restrict__ zh, _Float16* __restrict__ zl) {
    int i = blockIdx.x * 4 + (threadIdx.x >> 6);
    int lane = threadIdx.x & 63;
    int n = i >> 10;
    const float* xp = x + (size_t)i * D_DIM;
    const float* mp = mu + n * D_DIM;
    const float* sp = s + n * D_DIM;
    float acc = 0.f;
    #pragma unroll
    for (int c = 0; c < 2; ++c) {
        int d = c * 256 + lane * 4;
        float4 xv = *(const float4*)&xp[d];
        float4 mv = *(const float4*)&mp[d];
        float4 sv = *(const float4*)&sp[d];
        float z0 = (xv.x - mv.x) / sv.x;
        float z1 = (xv.y - mv.y) / sv.y;
        float z2 = (xv.z - mv.z) / sv.z;
        float z3 = (xv.w - mv.w) / sv.w;
        Split s0 = split16(z0), s1 = split16(z1), s2 = split16(z2), s3 = split16(z3);
        h4 hv, lv;
        hv[0] = s0.hi; hv[1] = s1.hi; hv[2] = s2.hi; hv[3] = s3.hi;
        lv[0] = s0.lo; lv[1] = s1.lo; lv[2] = s2.lo; lv[3] = s3.lo;
        *(h4*)&zh[(size_t)i * D_DIM + d] = hv;
        *(h4*)&zl[(size_t)i * D_DIM + d] = lv;
        acc += z0 * z0 + z1 * z1 + z2 * z2 + z3 * z3;
    }
    #pragma unroll
    for (int sft = 32; sft; sft >>= 1) acc += __shfl_xor(acc, sft, 64);
    if (lane == 0) cz[i] = acc;
}

// ---- MFMA fp16-split GEMM + argmin ----
__global__ __launch_bounds__(256, 2) void gemm_argmin(
    const _Float16* __restrict__ zh, const _Float16* __restrict__ zl,
    const _Float16* __restrict__ eh, const _Float16* __restrict__ el,
    const float* __restrict__ ce, const float* __restrict__ cz,
    unsigned long long* __restrict__ keys) {
    // rows padded to 40 halves (80B = 20 banks): b128 frag reads hit each bank
    // exactly 8x (balanced), and 80B is 16B-aligned for ds_read_b128.
    __shared__ _Float16 Ah[128][40], Al[128][40], Bh[128][40], Bl[128][40];
    int tid = threadIdx.x;
    int bid = blockIdx.x;
    int swz = (bid & 7) * 512 + (bid >> 3);   // XCD-chunked, bijective (4096%8==0)
    int n0 = (swz & 15) * 128;                // code tile
    int m0 = (swz >> 4) * 128;                // query-row tile

    f32x4 acc0[4][4], acc1[4][4];
    #pragma unroll
    for (int a = 0; a < 4; ++a)
        #pragma unroll
        for (int b = 0; b < 4; ++b) { acc0[a][b] = (f32x4)0.0f; acc1[a][b] = (f32x4)0.0f; }

    int w = tid >> 6, l = tid & 63;
    int wm = (w >> 1) * 64, wn = (w & 1) * 64;
    int fr = l & 15, fg = l >> 4;
    int srow = tid >> 1;

    for (int kc = 0; kc < 512; kc += 32) {
        __syncthreads();
        #pragma unroll
        for (int p = 0; p < 2; ++p) {
            int col = ((tid & 1) + 2 * p) * 8;
            size_t ga = (size_t)(m0 + srow) * D_DIM + (kc + col);
            size_t gb = (size_t)(n0 + srow) * D_DIM + (kc + col);
            h8 vah = *(const h8*)&zh[ga];
            h8 val = *(const h8*)&zl[ga];
            h8 vbh = *(const h8*)&eh[gb];
            h8 vbl = *(const h8*)&el[gb];
            *(h8*)&Ah[srow][col] = vah;
            *(h8*)&Al[srow][col] = val;
            *(h8*)&Bh[srow][col] = vbh;
            *(h8*)&Bl[srow][col] = vbl;
        }
        __syncthreads();
        h8 ah[4], al[4], bh[4], bl[4];
        #pragma unroll
        for (int i = 0; i < 4; ++i) {
            ah[i] = *(h8*)&Ah[wm + i * 16 + fr][fg * 8];
            al[i] = *(h8*)&Al[wm + i * 16 + fr][fg * 8];
            bh[i] = *(h8*)&Bh[wn + i * 16 + fr][fg * 8];
            bl[i] = *(h8*)&Bl[wn + i * 16 + fr][fg * 8];
        }
        #pragma unroll
        for (int mb = 0; mb < 4; ++mb)
            #pragma unroll
            for (int nb = 0; nb < 4; ++nb) {
                acc0[mb][nb] = __builtin_amdgcn_mfma_f32_16x16x32_f16(ah[mb], bh[nb], acc0[mb][nb], 0, 0, 0);
                acc1[mb][nb] = __builtin_amdgcn_mfma_f32_16x16x32_f16(ah[mb], bl[nb], acc1[mb][nb], 0, 0, 0);
                acc1[mb][nb] = __builtin_amdgcn_mfma_f32_16x16x32_f16(al[mb], bh[nb], acc1[mb][nb], 0, 0, 0);
            }
    }

    // epilogue: dist = (ce+cz) - 2*dot, dot = acc0 + acc1*2^-11
    #pragma unroll
    for (int mb = 0; mb < 4; ++mb) {
        #pragma unroll
        for (int r = 0; r < 4; ++r) {
            int q = m0 + wm + mb * 16 + fg * 4 + r;
            float czq = cz[q];
            unsigned long long best = ~0ULL;
            #pragma unroll
            for (int nb = 0; nb < 4; ++nb) {
                int j = n0 + wn + nb * 16 + fr;
                float dotv = acc0[mb][nb][r] + acc1[mb][nb][r] * (1.0f / 2048.0f);
                float dist = (ce[j] + czq) - 2.0f * dotv;
                unsigned long long key =
                    ((unsigned long long)__float_as_uint(dist) << 32) | (unsigned)j;
                if (key < best) best = key;
            }
            #pragma unroll
            for (int sft = 1; sft < 16; sft <<= 1) {
                unsigned long long o = __shfl_xor(best, sft, 64);
                if (o < best) best = o;
            }
            if (fr == 0) atomicMin(keys + q, best);
        }
    }
}

// ---- gather + STE output + loss + histogram (1 wave per row) ----
__global__ void output_kernel(const float* __restrict__ x, const float* __restrict__ mu,
                              const float* __restrict__ s, const float* __restrict__ emb,
                              const unsigned long long* __restrict__ keys,
                              float* __restrict__ out, float* __restrict__ loss_acc,
                              unsigned* __restrict__ hist) {
    int i = blockIdx.x * 4 + (threadIdx.x >> 6);
    int lane = threadIdx.x & 63;
    int n = i >> 10;
    unsigned idx = (unsigned)(keys[i] & 0xFFFFFFFFULL);
    float lsum = 0.f;
    #pragma unroll
    for (int c = 0; c < 2; ++c) {
        int d = c * 256 + lane * 4;
        float4 xv = *(const float4*)&x[(size_t)i * D_DIM + d];
        float4 mv = *(const float4*)&mu[n * D_DIM + d];
        float4 sv = *(const float4*)&s[n * D_DIM + d];
        float4 ev = *(const float4*)&emb[(size_t)idx * D_DIM + d];
        float z0 = (xv.x - mv.x) / sv.x;
        float z1 = (xv.y - mv.y) / sv.y;
        float z2 = (xv.z - mv.z) / sv.z;
        float z3 = (xv.w - mv.w) / sv.w;
        float o0 = ((z0 + (ev.x - z0)) + ev.x) * 0.5f;
        float o1 = ((z1 + (ev.y - z1)) + ev.y) * 0.5f;
        float o2 = ((z2 + (ev.z - z2)) + ev.z) * 0.5f;
        float o3 = ((z3 + (ev.w - z3)) + ev.w) * 0.5f;
        *(float4*)&out[(size_t)i * D_DIM + d] = make_float4(o0, o1, o2, o3);
        lsum += (z0 - ev.x) * (z0 - ev.x) + (z1 - ev.y) * (z1 - ev.y)
              + (z2 - ev.z) * (z2 - ev.z) + (z3 - ev.w) * (z3 - ev.w);
    }
    #pragma unroll
    for (int sft = 32; sft; sft >>= 1) lsum += __shfl_xor(lsum, sft, 64);
    if (lane == 0) {
        atomicAdd(loss_acc, lsum);
        atomicAdd(&hist[idx], 1u);
    }
}

// ---- scalars: loss mean + perplexity ----
__global__ void final_kernel(const unsigned* __restrict__ hist,
                             const float* __restrict__ loss_acc, float* __restrict__ out) {
    float h = 0.f;
    for (int b = threadIdx.x; b < M_CODES; b += 256) {
        float p = (float)hist[b] * (1.0f / 32768.0f);
        h += p * logf(p + 1e-10f);
    }
    h = block_reduce_sum_256(h);
    if (threadIdx.x == 0) {
        out[TOTAL] = loss_acc[0] * (1.0f / 16777216.0f);
        out[TOTAL + 1] = expf(-h);
    }
}

extern "C" void kernel_launch(void* const* d_in, const int* in_sizes, int n_in,
                              void* d_out, int out_size, void* d_ws, size_t ws_size,
                              hipStream_t stream) {
    (void)in_sizes; (void)n_in; (void)out_size; (void)ws_size;
    const float* x = (const float*)d_in[0];
    const float* emb = (const float*)d_in[1];
    float* out = (float*)d_out;
    char* ws = (char*)d_ws;
    float* mu   = (float*)(ws + WS_MU);
    float* s    = (float*)(ws + WS_S);
    float* cz   = (float*)(ws + WS_CZ);
    float* ce   = (float*)(ws + WS_CE);
    unsigned long long* keys = (unsigned long long*)(ws + WS_KEYS);
    _Float16* eh = (_Float16*)(ws + WS_EH);
    _Float16* el = (_Float16*)(ws + WS_EL);
    unsigned* hist = (unsigned*)(ws + WS_HIST);
    float* loss_acc = (float*)(ws + WS_LOSS);
    // z fp16 split staged in d_out (64MB exactly), overwritten by output_kernel
    _Float16* zh = (_Float16*)d_out;
    _Float16* zl = zh + TOTAL;

    (void)hipMemsetAsync(ws + WS_KEYS, 0xFF, 262144, stream);
    (void)hipMemsetAsync(ws + WS_HIST, 0x00, 8192 + 16, stream);

    stats_kernel<<<dim3(8, 32), 256, 0, stream>>>(x, mu, s);
    codebook_kernel<<<M_CODES, 256, 0, stream>>>(emb, eh, el, ce);
    cz_split_kernel<<<NT / 4, 256, 0, stream>>>(x, mu, s, cz, zh, zl);
    gemm_argmin<<<4096, 256, 0, stream>>>(zh, zl, eh, el, ce, cz, keys);
    output_kernel<<<NT / 4, 256, 0, stream>>>(x, mu, s, emb, keys, out, loss_acc, hist);
    final_kernel<<<1, 256, 0, stream>>>(hist, loss_acc, out);
}

// Round 4
// 435.692 us; speedup vs baseline: 2.8483x; 1.8746x over previous
//
#include <hip/hip_runtime.h>

#define T_DIM 1024
#define D_DIM 512
#define M_CODES 2048
#define NT 32768            // 32*1024 query rows
#define TOTAL 16777216      // NT*D_DIM

typedef _Float16 h2 __attribute__((ext_vector_type(2)));
typedef _Float16 h4 __attribute__((ext_vector_type(4)));
typedef _Float16 h8 __attribute__((ext_vector_type(8)));
typedef float f32x4 __attribute__((ext_vector_type(4)));

// ---- workspace layout (bytes) ----
#define WS_MU    0                        // 16384 f32
#define WS_S     65536                    // 16384 f32
#define WS_CZ    131072                   // 32768 f32
#define WS_CE    262144                   // 2048 f32
#define WS_KEYS  270336                   // 32768 u64
#define WS_EH    532480                   // 2048*512 f16
#define WS_EL    (532480 + 2097152)       // 2048*512 f16
#define WS_HIST  (532480 + 4194304)       // 2048 u32
#define WS_LPART (WS_HIST + 8192)         // 8192 f32 per-block loss partials

__device__ __forceinline__ float block_reduce_sum_256(float v) {
    #pragma unroll
    for (int s = 32; s; s >>= 1) v += __shfl_xor(v, s, 64);
    __shared__ float ls[4];
    int w = threadIdx.x >> 6;
    if ((threadIdx.x & 63) == 0) ls[w] = v;
    __syncthreads();
    float r = (ls[0] + ls[1]) + (ls[2] + ls[3]);
    __syncthreads();
    return r;
}

struct Split { _Float16 hi, lo; };
// v = hi + lo*2^-11 with hi,lo fp16 (lo pre-scaled by 2^11 to stay normal)
__device__ __forceinline__ Split split16(float v) {
    Split r;
    _Float16 h = (_Float16)v;
    float res = v - (float)h;            // exact (Sterbenz)
    r.hi = h;
    r.lo = (_Float16)(res * 2048.0f);    // scale exact
    return r;
}

// ---- instance-norm stats over T per (n,d): mu, s=std+eps ----
__global__ void stats_kernel(const float* __restrict__ x,
                             float* __restrict__ mu_o, float* __restrict__ s_o) {
    int n = blockIdx.y;
    int lane = threadIdx.x & 63;
    int d = blockIdx.x * 64 + lane;
    int tg = threadIdx.x >> 6;
    const float* xp = x + (size_t)n * (T_DIM * D_DIM) + d;
    float sum = 0.f, sq = 0.f;
    int t0 = tg * 256;
    for (int it = 0; it < 256; ++it) {
        float v = xp[(size_t)(t0 + it) * D_DIM];
        sum += v; sq += v * v;
    }
    __shared__ float ssum[4][64], ssq[4][64];
    ssum[tg][lane] = sum;
    ssq[tg][lane] = sq;
    __syncthreads();
    if (threadIdx.x < 64) {
        int l = threadIdx.x;
        float s1 = (ssum[0][l] + ssum[1][l]) + (ssum[2][l] + ssum[3][l]);
        float q1 = (ssq[0][l] + ssq[1][l]) + (ssq[2][l] + ssq[3][l]);
        float mu = s1 * (1.0f / 1024.0f);
        float var = (q1 - 1024.0f * mu * mu) * (1.0f / 1023.0f);
        var = fmaxf(var, 0.0f);
        float sd = sqrtf(var) + 1e-5f;
        int nd = n * D_DIM + blockIdx.x * 64 + l;
        mu_o[nd] = mu; s_o[nd] = sd;
    }
}

// ---- codebook prep: emb_n split to f16 hi/lo, ce = sum(emb_n^2) ----
__global__ void codebook_kernel(const float* __restrict__ emb,
                                _Float16* __restrict__ eh, _Float16* __restrict__ el,
                                float* __restrict__ ce) {
    int j = blockIdx.x;
    int d = threadIdx.x * 2;
    float2 e = *(const float2*)&emb[(size_t)j * D_DIM + d];
    float sq = e.x * e.x + e.y * e.y;
    float norm2 = block_reduce_sum_256(sq);
    float den = sqrtf(norm2) + 1e-4f;
    float en0 = e.x / den, en1 = e.y / den;
    Split s0 = split16(en0), s1 = split16(en1);
    h2 hv, lv;
    hv[0] = s0.hi; hv[1] = s1.hi;
    lv[0] = s0.lo; lv[1] = s1.lo;
    *(h2*)&eh[(size_t)j * D_DIM + d] = hv;
    *(h2*)&el[(size_t)j * D_DIM + d] = lv;
    float cep = en0 * en0 + en1 * en1;
    float cesum = block_reduce_sum_256(cep);
    if (threadIdx.x == 0) ce[j] = cesum;
}

// ---- z = (x-mu)/s exactly like ref; write f16 split + cz = ||z||^2 ----
__global__ void cz_split_kernel(const float* __restrict__ x, const float* __restrict__ mu,
                                const float* __restrict__ s, float* __restrict__ cz,
                                _Float16* __restrict__ zh, _Float16* __restrict__ zl) {
    int i = blockIdx.x * 4 + (threadIdx.x >> 6);
    int lane = threadIdx.x & 63;
    int n = i >> 10;
    const float* xp = x + (size_t)i * D_DIM;
    const float* mp = mu + n * D_DIM;
    const float* sp = s + n * D_DIM;
    float acc = 0.f;
    #pragma unroll
    for (int c = 0; c < 2; ++c) {
        int d = c * 256 + lane * 4;
        float4 xv = *(const float4*)&xp[d];
        float4 mv = *(const float4*)&mp[d];
        float4 sv = *(const float4*)&sp[d];
        float z0 = (xv.x - mv.x) / sv.x;
        float z1 = (xv.y - mv.y) / sv.y;
        float z2 = (xv.z - mv.z) / sv.z;
        float z3 = (xv.w - mv.w) / sv.w;
        Split s0 = split16(z0), s1 = split16(z1), s2 = split16(z2), s3 = split16(z3);
        h4 hv, lv;
        hv[0] = s0.hi; hv[1] = s1.hi; hv[2] = s2.hi; hv[3] = s3.hi;
        lv[0] = s0.lo; lv[1] = s1.lo; lv[2] = s2.lo; lv[3] = s3.lo;
        *(h4*)&zh[(size_t)i * D_DIM + d] = hv;
        *(h4*)&zl[(size_t)i * D_DIM + d] = lv;
        acc += z0 * z0 + z1 * z1 + z2 * z2 + z3 * z3;
    }
    #pragma unroll
    for (int sft = 32; sft; sft >>= 1) acc += __shfl_xor(acc, sft, 64);
    if (lane == 0) cz[i] = acc;
}

// ---- MFMA fp16-split GEMM + argmin ----
__global__ __launch_bounds__(256, 2) void gemm_argmin(
    const _Float16* __restrict__ zh, const _Float16* __restrict__ zl,
    const _Float16* __restrict__ eh, const _Float16* __restrict__ el,
    const float* __restrict__ ce, const float* __restrict__ cz,
    unsigned long long* __restrict__ keys) {
    // rows padded to 40 halves (80B = 20 banks): b128 frag reads hit each bank
    // exactly 8x (balanced), and 80B is 16B-aligned for ds_read_b128.
    __shared__ _Float16 Ah[128][40], Al[128][40], Bh[128][40], Bl[128][40];
    int tid = threadIdx.x;
    int bid = blockIdx.x;
    int swz = (bid & 7) * 512 + (bid >> 3);   // XCD-chunked, bijective (4096%8==0)
    int n0 = (swz & 15) * 128;                // code tile
    int m0 = (swz >> 4) * 128;                // query-row tile

    f32x4 acc0[4][4], acc1[4][4];
    #pragma unroll
    for (int a = 0; a < 4; ++a)
        #pragma unroll
        for (int b = 0; b < 4; ++b) { acc0[a][b] = (f32x4)0.0f; acc1[a][b] = (f32x4)0.0f; }

    int w = tid >> 6, l = tid & 63;
    int wm = (w >> 1) * 64, wn = (w & 1) * 64;
    int fr = l & 15, fg = l >> 4;
    int srow = tid >> 1;

    for (int kc = 0; kc < 512; kc += 32) {
        __syncthreads();
        #pragma unroll
        for (int p = 0; p < 2; ++p) {
            int col = ((tid & 1) + 2 * p) * 8;
            size_t ga = (size_t)(m0 + srow) * D_DIM + (kc + col);
            size_t gb = (size_t)(n0 + srow) * D_DIM + (kc + col);
            h8 vah = *(const h8*)&zh[ga];
            h8 val = *(const h8*)&zl[ga];
            h8 vbh = *(const h8*)&eh[gb];
            h8 vbl = *(const h8*)&el[gb];
            *(h8*)&Ah[srow][col] = vah;
            *(h8*)&Al[srow][col] = val;
            *(h8*)&Bh[srow][col] = vbh;
            *(h8*)&Bl[srow][col] = vbl;
        }
        __syncthreads();
        h8 ah[4], al[4], bh[4], bl[4];
        #pragma unroll
        for (int i = 0; i < 4; ++i) {
            ah[i] = *(h8*)&Ah[wm + i * 16 + fr][fg * 8];
            al[i] = *(h8*)&Al[wm + i * 16 + fr][fg * 8];
            bh[i] = *(h8*)&Bh[wn + i * 16 + fr][fg * 8];
            bl[i] = *(h8*)&Bl[wn + i * 16 + fr][fg * 8];
        }
        #pragma unroll
        for (int mb = 0; mb < 4; ++mb)
            #pragma unroll
            for (int nb = 0; nb < 4; ++nb) {
                acc0[mb][nb] = __builtin_amdgcn_mfma_f32_16x16x32_f16(ah[mb], bh[nb], acc0[mb][nb], 0, 0, 0);
                acc1[mb][nb] = __builtin_amdgcn_mfma_f32_16x16x32_f16(ah[mb], bl[nb], acc1[mb][nb], 0, 0, 0);
                acc1[mb][nb] = __builtin_amdgcn_mfma_f32_16x16x32_f16(al[mb], bh[nb], acc1[mb][nb], 0, 0, 0);
            }
    }

    // epilogue: dist = (ce+cz) - 2*dot, dot = acc0 + acc1*2^-11
    #pragma unroll
    for (int mb = 0; mb < 4; ++mb) {
        #pragma unroll
        for (int r = 0; r < 4; ++r) {
            int q = m0 + wm + mb * 16 + fg * 4 + r;
            float czq = cz[q];
            unsigned long long best = ~0ULL;
            #pragma unroll
            for (int nb = 0; nb < 4; ++nb) {
                int j = n0 + wn + nb * 16 + fr;
                float dotv = acc0[mb][nb][r] + acc1[mb][nb][r] * (1.0f / 2048.0f);
                float dist = (ce[j] + czq) - 2.0f * dotv;
                unsigned long long key =
                    ((unsigned long long)__float_as_uint(dist) << 32) | (unsigned)j;
                if (key < best) best = key;
            }
            #pragma unroll
            for (int sft = 1; sft < 16; sft <<= 1) {
                unsigned long long o = __shfl_xor(best, sft, 64);
                if (o < best) best = o;
            }
            if (fr == 0) atomicMin(keys + q, best);
        }
    }
}

// ---- gather + STE output + loss partials + histogram (1 wave per row) ----
__global__ void output_kernel(const float* __restrict__ x, const float* __restrict__ mu,
                              const float* __restrict__ s, const float* __restrict__ emb,
                              const unsigned long long* __restrict__ keys,
                              float* __restrict__ out, float* __restrict__ loss_part,
                              unsigned* __restrict__ hist) {
    int i = blockIdx.x * 4 + (threadIdx.x >> 6);
    int lane = threadIdx.x & 63;
    int n = i >> 10;
    unsigned idx = (unsigned)(keys[i] & 0xFFFFFFFFULL);
    float lsum = 0.f;
    #pragma unroll
    for (int c = 0; c < 2; ++c) {
        int d = c * 256 + lane * 4;
        float4 xv = *(const float4*)&x[(size_t)i * D_DIM + d];
        float4 mv = *(const float4*)&mu[n * D_DIM + d];
        float4 sv = *(const float4*)&s[n * D_DIM + d];
        float4 ev = *(const float4*)&emb[(size_t)idx * D_DIM + d];
        float z0 = (xv.x - mv.x) / sv.x;
        float z1 = (xv.y - mv.y) / sv.y;
        float z2 = (xv.z - mv.z) / sv.z;
        float z3 = (xv.w - mv.w) / sv.w;
        float o0 = ((z0 + (ev.x - z0)) + ev.x) * 0.5f;
        float o1 = ((z1 + (ev.y - z1)) + ev.y) * 0.5f;
        float o2 = ((z2 + (ev.z - z2)) + ev.z) * 0.5f;
        float o3 = ((z3 + (ev.w - z3)) + ev.w) * 0.5f;
        *(float4*)&out[(size_t)i * D_DIM + d] = make_float4(o0, o1, o2, o3);
        lsum += (z0 - ev.x) * (z0 - ev.x) + (z1 - ev.y) * (z1 - ev.y)
              + (z2 - ev.z) * (z2 - ev.z) + (z3 - ev.w) * (z3 - ev.w);
    }
    #pragma unroll
    for (int sft = 32; sft; sft >>= 1) lsum += __shfl_xor(lsum, sft, 64);
    __shared__ float ls[4];
    if (lane == 0) {
        ls[threadIdx.x >> 6] = lsum;
        atomicAdd(&hist[idx], 1u);   // scattered over 2048 bins: cheap
    }
    __syncthreads();
    if (threadIdx.x == 0)
        loss_part[blockIdx.x] = (ls[0] + ls[1]) + (ls[2] + ls[3]);
}

// ---- scalars: loss mean (from partials) + perplexity ----
__global__ void final_kernel(const unsigned* __restrict__ hist,
                             const float* __restrict__ loss_part, float* __restrict__ out) {
    float h = 0.f;
    for (int b = threadIdx.x; b < M_CODES; b += 256) {
        float p = (float)hist[b] * (1.0f / 32768.0f);
        h += p * logf(p + 1e-10f);
    }
    h = block_reduce_sum_256(h);
    float lsum = 0.f;
    for (int b = threadIdx.x; b < NT / 4; b += 256) lsum += loss_part[b];
    lsum = block_reduce_sum_256(lsum);
    if (threadIdx.x == 0) {
        out[TOTAL] = lsum * (1.0f / 16777216.0f);
        out[TOTAL + 1] = expf(-h);
    }
}

extern "C" void kernel_launch(void* const* d_in, const int* in_sizes, int n_in,
                              void* d_out, int out_size, void* d_ws, size_t ws_size,
                              hipStream_t stream) {
    (void)in_sizes; (void)n_in; (void)out_size; (void)ws_size;
    const float* x = (const float*)d_in[0];
    const float* emb = (const float*)d_in[1];
    float* out = (float*)d_out;
    char* ws = (char*)d_ws;
    float* mu   = (float*)(ws + WS_MU);
    float* s    = (float*)(ws + WS_S);
    float* cz   = (float*)(ws + WS_CZ);
    float* ce   = (float*)(ws + WS_CE);
    unsigned long long* keys = (unsigned long long*)(ws + WS_KEYS);
    _Float16* eh = (_Float16*)(ws + WS_EH);
    _Float16* el = (_Float16*)(ws + WS_EL);
    unsigned* hist = (unsigned*)(ws + WS_HIST);
    float* loss_part = (float*)(ws + WS_LPART);
    // z fp16 split staged in d_out (64MB exactly), overwritten by output_kernel
    _Float16* zh = (_Float16*)d_out;
    _Float16* zl = zh + TOTAL;

    (void)hipMemsetAsync(ws + WS_KEYS, 0xFF, 262144, stream);
    (void)hipMemsetAsync(ws + WS_HIST, 0x00, 8192, stream);

    stats_kernel<<<dim3(8, 32), 256, 0, stream>>>(x, mu, s);
    codebook_kernel<<<M_CODES, 256, 0, stream>>>(emb, eh, el, ce);
    cz_split_kernel<<<NT / 4, 256, 0, stream>>>(x, mu, s, cz, zh, zl);
    gemm_argmin<<<4096, 256, 0, stream>>>(zh, zl, eh, el, ce, cz, keys);
    output_kernel<<<NT / 4, 256, 0, stream>>>(x, mu, s, emb, keys, out, loss_part, hist);
    final_kernel<<<1, 256, 0, stream>>>(hist, loss_part, out);
}

// Round 5
// 386.592 us; speedup vs baseline: 3.2100x; 1.1270x over previous
//
#include <hip/hip_runtime.h>

#define T_DIM 1024
#define D_DIM 512
#define M_CODES 2048
#define NT 32768            // 32*1024 query rows
#define TOTAL 16777216      // NT*D_DIM

typedef _Float16 h2 __attribute__((ext_vector_type(2)));
typedef _Float16 h4 __attribute__((ext_vector_type(4)));
typedef _Float16 h8 __attribute__((ext_vector_type(8)));
typedef float f32x4 __attribute__((ext_vector_type(4)));
typedef unsigned int u32;

// ---- workspace layout (bytes) ----
#define WS_MU    0                        // 16384 f32
#define WS_S     65536                    // 16384 f32
#define WS_CZ    131072                   // 32768 f32
#define WS_CE    262144                   // 2048 f32
#define WS_KEYS  270336                   // 32768 u64
#define WS_EH    532480                   // 2048*512 f16
#define WS_EL    (532480 + 2097152)       // 2048*512 f16
#define WS_HIST  (532480 + 4194304)       // 2048 u32
#define WS_LPART (WS_HIST + 8192)         // 8192 f32 per-block loss partials

// async global->LDS, 16B per lane; dst must be wave-uniform (HW adds lane*16)
__device__ __forceinline__ void gload16(const void* g, void* l) {
    __builtin_amdgcn_global_load_lds(
        (const __attribute__((address_space(1))) u32*)g,
        (__attribute__((address_space(3))) u32*)l, 16, 0, 0);
}

__device__ __forceinline__ float block_reduce_sum_256(float v) {
    #pragma unroll
    for (int s = 32; s; s >>= 1) v += __shfl_xor(v, s, 64);
    __shared__ float ls[4];
    int w = threadIdx.x >> 6;
    if ((threadIdx.x & 63) == 0) ls[w] = v;
    __syncthreads();
    float r = (ls[0] + ls[1]) + (ls[2] + ls[3]);
    __syncthreads();
    return r;
}

struct Split { _Float16 hi, lo; };
// v = hi + lo*2^-11 with hi,lo fp16 (lo pre-scaled by 2^11 to stay normal)
__device__ __forceinline__ Split split16(float v) {
    Split r;
    _Float16 h = (_Float16)v;
    float res = v - (float)h;            // exact (Sterbenz)
    r.hi = h;
    r.lo = (_Float16)(res * 2048.0f);    // scale exact
    return r;
}

// ---- instance-norm stats over T per (n,d): mu, s=std+eps ----
__global__ void stats_kernel(const float* __restrict__ x,
                             float* __restrict__ mu_o, float* __restrict__ s_o) {
    int n = blockIdx.y;
    int lane = threadIdx.x & 63;
    int d = blockIdx.x * 64 + lane;
    int tg = threadIdx.x >> 6;
    const float* xp = x + (size_t)n * (T_DIM * D_DIM) + d;
    float sum = 0.f, sq = 0.f;
    int t0 = tg * 256;
    for (int it = 0; it < 256; ++it) {
        float v = xp[(size_t)(t0 + it) * D_DIM];
        sum += v; sq += v * v;
    }
    __shared__ float ssum[4][64], ssq[4][64];
    ssum[tg][lane] = sum;
    ssq[tg][lane] = sq;
    __syncthreads();
    if (threadIdx.x < 64) {
        int l = threadIdx.x;
        float s1 = (ssum[0][l] + ssum[1][l]) + (ssum[2][l] + ssum[3][l]);
        float q1 = (ssq[0][l] + ssq[1][l]) + (ssq[2][l] + ssq[3][l]);
        float mu = s1 * (1.0f / 1024.0f);
        float var = (q1 - 1024.0f * mu * mu) * (1.0f / 1023.0f);
        var = fmaxf(var, 0.0f);
        float sd = sqrtf(var) + 1e-5f;
        int nd = n * D_DIM + blockIdx.x * 64 + l;
        mu_o[nd] = mu; s_o[nd] = sd;
    }
}

// ---- codebook prep: emb_n split to f16 hi/lo, ce = sum(emb_n^2) ----
__global__ void codebook_kernel(const float* __restrict__ emb,
                                _Float16* __restrict__ eh, _Float16* __restrict__ el,
                                float* __restrict__ ce) {
    int j = blockIdx.x;
    int d = threadIdx.x * 2;
    float2 e = *(const float2*)&emb[(size_t)j * D_DIM + d];
    float sq = e.x * e.x + e.y * e.y;
    float norm2 = block_reduce_sum_256(sq);
    float den = sqrtf(norm2) + 1e-4f;
    float en0 = e.x / den, en1 = e.y / den;
    Split s0 = split16(en0), s1 = split16(en1);
    h2 hv, lv;
    hv[0] = s0.hi; hv[1] = s1.hi;
    lv[0] = s0.lo; lv[1] = s1.lo;
    *(h2*)&eh[(size_t)j * D_DIM + d] = hv;
    *(h2*)&el[(size_t)j * D_DIM + d] = lv;
    float cep = en0 * en0 + en1 * en1;
    float cesum = block_reduce_sum_256(cep);
    if (threadIdx.x == 0) ce[j] = cesum;
}

// ---- z = (x-mu)/s exactly like ref; write f16 split + cz = ||z||^2 ----
__global__ void cz_split_kernel(const float* __restrict__ x, const float* __restrict__ mu,
                                const float* __restrict__ s, float* __restrict__ cz,
                                _Float16* __restrict__ zh, _Float16* __restrict__ zl) {
    int i = blockIdx.x * 4 + (threadIdx.x >> 6);
    int lane = threadIdx.x & 63;
    int n = i >> 10;
    const float* xp = x + (size_t)i * D_DIM;
    const float* mp = mu + n * D_DIM;
    const float* sp = s + n * D_DIM;
    float acc = 0.f;
    #pragma unroll
    for (int c = 0; c < 2; ++c) {
        int d = c * 256 + lane * 4;
        float4 xv = *(const float4*)&xp[d];
        float4 mv = *(const float4*)&mp[d];
        float4 sv = *(const float4*)&sp[d];
        float z0 = (xv.x - mv.x) / sv.x;
        float z1 = (xv.y - mv.y) / sv.y;
        float z2 = (xv.z - mv.z) / sv.z;
        float z3 = (xv.w - mv.w) / sv.w;
        Split s0 = split16(z0), s1 = split16(z1), s2 = split16(z2), s3 = split16(z3);
        h4 hv, lv;
        hv[0] = s0.hi; hv[1] = s1.hi; hv[2] = s2.hi; hv[3] = s3.hi;
        lv[0] = s0.lo; lv[1] = s1.lo; lv[2] = s2.lo; lv[3] = s3.lo;
        *(h4*)&zh[(size_t)i * D_DIM + d] = hv;
        *(h4*)&zl[(size_t)i * D_DIM + d] = lv;
        acc += z0 * z0 + z1 * z1 + z2 * z2 + z3 * z3;
    }
    #pragma unroll
    for (int sft = 32; sft; sft >>= 1) acc += __shfl_xor(acc, sft, 64);
    if (lane == 0) cz[i] = acc;
}

// ---- MFMA fp16-split GEMM + argmin, global_load_lds + swizzled linear LDS ----
// LDS per array: 128 rows x 4 h8-slots (64B rows). Swizzle: LDS slot s of row r
// holds global slot s ^ ((r>>1)&3) (same involution on stage-source and read).
__global__ __launch_bounds__(256, 2) void gemm_argmin(
    const _Float16* __restrict__ zh, const _Float16* __restrict__ zl,
    const _Float16* __restrict__ eh, const _Float16* __restrict__ el,
    const float* __restrict__ ce, const float* __restrict__ cz,
    unsigned long long* __restrict__ keys) {
    __shared__ h8 smem[2][4][512];     // [dbuf][Ah,Al,Bh,Bl][row*4+slot] = 64KB
    int tid = threadIdx.x;
    int bid = blockIdx.x;
    int swz = (bid & 7) * 512 + (bid >> 3);   // XCD-chunked, bijective (4096%8==0)
    int n0 = (swz & 15) * 128;                // code tile
    int m0 = (swz >> 4) * 128;                // query-row tile

    f32x4 acc0[4][4], acc1[4][4];
    #pragma unroll
    for (int a = 0; a < 4; ++a)
        #pragma unroll
        for (int b = 0; b < 4; ++b) { acc0[a][b] = (f32x4)0.0f; acc1[a][b] = (f32x4)0.0f; }

    int w = tid >> 6, l = tid & 63;
    int wm = (w >> 1) * 64, wn = (w & 1) * 64;
    int fr = l & 15, fg = l >> 4;

    // staging geometry: wave w stages rows 32w..32w+31 (2 instrs of 16 rows/array)
    int rl = 32 * w + (l >> 2);                       // lane's source row (q=0)
    int c0 = (((l & 3) ^ ((rl >> 1) & 3)) << 3);      // swizzled col (halves); same for q=1
    size_t offA0 = (size_t)(m0 + rl) * D_DIM + c0;
    size_t offB0 = (size_t)(n0 + rl) * D_DIM + c0;

    #define STAGE(buf, kc)                                                        \
        _Pragma("unroll")                                                         \
        for (int q = 0; q < 2; ++q) {                                             \
            size_t oa = offA0 + (size_t)q * 16 * D_DIM + (kc);                    \
            size_t ob = offB0 + (size_t)q * 16 * D_DIM + (kc);                    \
            int db = (32 * w + 16 * q) * 4;                                       \
            gload16(zh + oa, &smem[buf][0][db]);                                  \
            gload16(zl + oa, &smem[buf][1][db]);                                  \
            gload16(eh + ob, &smem[buf][2][db]);                                  \
            gload16(el + ob, &smem[buf][3][db]);                                  \
        }

    STAGE(0, 0)
    __syncthreads();

    int cur = 0;
    for (int t = 0; t < 16; ++t) {
        if (t < 15) { STAGE(cur ^ 1, (t + 1) * 32) }
        h8 ah[4], al[4], bh[4], bl[4];
        #pragma unroll
        for (int i = 0; i < 4; ++i) {
            int ra = wm + i * 16 + fr;
            int sa = ra * 4 + (fg ^ ((ra >> 1) & 3));
            ah[i] = smem[cur][0][sa];
            al[i] = smem[cur][1][sa];
            int rb = wn + i * 16 + fr;
            int sb = rb * 4 + (fg ^ ((rb >> 1) & 3));
            bh[i] = smem[cur][2][sb];
            bl[i] = smem[cur][3][sb];
        }
        #pragma unroll
        for (int mb = 0; mb < 4; ++mb)
            #pragma unroll
            for (int nb = 0; nb < 4; ++nb) {
                acc0[mb][nb] = __builtin_amdgcn_mfma_f32_16x16x32_f16(ah[mb], bh[nb], acc0[mb][nb], 0, 0, 0);
                acc1[mb][nb] = __builtin_amdgcn_mfma_f32_16x16x32_f16(ah[mb], bl[nb], acc1[mb][nb], 0, 0, 0);
                acc1[mb][nb] = __builtin_amdgcn_mfma_f32_16x16x32_f16(al[mb], bh[nb], acc1[mb][nb], 0, 0, 0);
            }
        __syncthreads();   // drains vmcnt: buf cur^1 fully staged; cur free
        cur ^= 1;
    }

    // epilogue: dist = (ce+cz) - 2*dot, dot = acc0 + acc1*2^-11
    #pragma unroll
    for (int mb = 0; mb < 4; ++mb) {
        #pragma unroll
        for (int r = 0; r < 4; ++r) {
            int q = m0 + wm + mb * 16 + fg * 4 + r;
            float czq = cz[q];
            unsigned long long best = ~0ULL;
            #pragma unroll
            for (int nb = 0; nb < 4; ++nb) {
                int j = n0 + wn + nb * 16 + fr;
                float dotv = acc0[mb][nb][r] + acc1[mb][nb][r] * (1.0f / 2048.0f);
                float dist = (ce[j] + czq) - 2.0f * dotv;
                unsigned long long key =
                    ((unsigned long long)__float_as_uint(dist) << 32) | (unsigned)j;
                if (key < best) best = key;
            }
            #pragma unroll
            for (int sft = 1; sft < 16; sft <<= 1) {
                unsigned long long o = __shfl_xor(best, sft, 64);
                if (o < best) best = o;
            }
            if (fr == 0) atomicMin(keys + q, best);
        }
    }
    #undef STAGE
}

// ---- gather + STE output + loss partials + histogram (1 wave per row) ----
__global__ void output_kernel(const float* __restrict__ x, const float* __restrict__ mu,
                              const float* __restrict__ s, const float* __restrict__ emb,
                              const unsigned long long* __restrict__ keys,
                              float* __restrict__ out, float* __restrict__ loss_part,
                              unsigned* __restrict__ hist) {
    int i = blockIdx.x * 4 + (threadIdx.x >> 6);
    int lane = threadIdx.x & 63;
    int n = i >> 10;
    unsigned idx = (unsigned)(keys[i] & 0xFFFFFFFFULL);
    float lsum = 0.f;
    #pragma unroll
    for (int c = 0; c < 2; ++c) {
        int d = c * 256 + lane * 4;
        float4 xv = *(const float4*)&x[(size_t)i * D_DIM + d];
        float4 mv = *(const float4*)&mu[n * D_DIM + d];
        float4 sv = *(const float4*)&s[n * D_DIM + d];
        float4 ev = *(const float4*)&emb[(size_t)idx * D_DIM + d];
        float z0 = (xv.x - mv.x) / sv.x;
        float z1 = (xv.y - mv.y) / sv.y;
        float z2 = (xv.z - mv.z) / sv.z;
        float z3 = (xv.w - mv.w) / sv.w;
        float o0 = ((z0 + (ev.x - z0)) + ev.x) * 0.5f;
        float o1 = ((z1 + (ev.y - z1)) + ev.y) * 0.5f;
        float o2 = ((z2 + (ev.z - z2)) + ev.z) * 0.5f;
        float o3 = ((z3 + (ev.w - z3)) + ev.w) * 0.5f;
        *(float4*)&out[(size_t)i * D_DIM + d] = make_float4(o0, o1, o2, o3);
        lsum += (z0 - ev.x) * (z0 - ev.x) + (z1 - ev.y) * (z1 - ev.y)
              + (z2 - ev.z) * (z2 - ev.z) + (z3 - ev.w) * (z3 - ev.w);
    }
    #pragma unroll
    for (int sft = 32; sft; sft >>= 1) lsum += __shfl_xor(lsum, sft, 64);
    __shared__ float ls[4];
    if (lane == 0) {
        ls[threadIdx.x >> 6] = lsum;
        atomicAdd(&hist[idx], 1u);   // scattered over 2048 bins: cheap
    }
    __syncthreads();
    if (threadIdx.x == 0)
        loss_part[blockIdx.x] = (ls[0] + ls[1]) + (ls[2] + ls[3]);
}

// ---- scalars: loss mean (from partials) + perplexity ----
__global__ void final_kernel(const unsigned* __restrict__ hist,
                             const float* __restrict__ loss_part, float* __restrict__ out) {
    float h = 0.f;
    for (int b = threadIdx.x; b < M_CODES; b += 256) {
        float p = (float)hist[b] * (1.0f / 32768.0f);
        h += p * logf(p + 1e-10f);
    }
    h = block_reduce_sum_256(h);
    float lsum = 0.f;
    for (int b = threadIdx.x; b < NT / 4; b += 256) lsum += loss_part[b];
    lsum = block_reduce_sum_256(lsum);
    if (threadIdx.x == 0) {
        out[TOTAL] = lsum * (1.0f / 16777216.0f);
        out[TOTAL + 1] = expf(-h);
    }
}

extern "C" void kernel_launch(void* const* d_in, const int* in_sizes, int n_in,
                              void* d_out, int out_size, void* d_ws, size_t ws_size,
                              hipStream_t stream) {
    (void)in_sizes; (void)n_in; (void)out_size; (void)ws_size;
    const float* x = (const float*)d_in[0];
    const float* emb = (const float*)d_in[1];
    float* out = (float*)d_out;
    char* ws = (char*)d_ws;
    float* mu   = (float*)(ws + WS_MU);
    float* s    = (float*)(ws + WS_S);
    float* cz   = (float*)(ws + WS_CZ);
    float* ce   = (float*)(ws + WS_CE);
    unsigned long long* keys = (unsigned long long*)(ws + WS_KEYS);
    _Float16* eh = (_Float16*)(ws + WS_EH);
    _Float16* el = (_Float16*)(ws + WS_EL);
    unsigned* hist = (unsigned*)(ws + WS_HIST);
    float* loss_part = (float*)(ws + WS_LPART);
    // z fp16 split staged in d_out (64MB exactly), overwritten by output_kernel
    _Float16* zh = (_Float16*)d_out;
    _Float16* zl = zh + TOTAL;

    (void)hipMemsetAsync(ws + WS_KEYS, 0xFF, 262144, stream);
    (void)hipMemsetAsync(ws + WS_HIST, 0x00, 8192, stream);

    stats_kernel<<<dim3(8, 32), 256, 0, stream>>>(x, mu, s);
    codebook_kernel<<<M_CODES, 256, 0, stream>>>(emb, eh, el, ce);
    cz_split_kernel<<<NT / 4, 256, 0, stream>>>(x, mu, s, cz, zh, zl);
    gemm_argmin<<<4096, 256, 0, stream>>>(zh, zl, eh, el, ce, cz, keys);
    output_kernel<<<NT / 4, 256, 0, stream>>>(x, mu, s, emb, keys, out, loss_part, hist);
    final_kernel<<<1, 256, 0, stream>>>(hist, loss_part, out);
}